// Round 1
// baseline (4158.630 us; speedup 1.0000x reference)
//
#include <hip/hip_runtime.h>

#define T_SEQ 1024
#define NBATCH 256
#define DIN 128
#define HID 64
#define DOUT 128

// ---------------- fast math helpers ----------------
__device__ __forceinline__ float rcp_f(float x) { return __builtin_amdgcn_rcpf(x); }

// tanh(x) = 1 - 2/(1+e^{2x});  inf-safe: e^{2x}=inf -> rcp=0 -> 1 ; e^{2x}=0 -> -1
__device__ __forceinline__ float tanh_f(float x) {
  float m = __expf(2.0f * x);
  return fmaf(-2.0f, rcp_f(1.0f + m), 1.0f);
}

// ds_swizzle broadcast within lane-groups of 4 (BitMode: and=0x1C, or=sel)
template<int IMM>
__device__ __forceinline__ float swz(float v) {
  return __uint_as_float((unsigned)__builtin_amdgcn_ds_swizzle((int)__float_as_uint(v), IMM));
}

// ---------------- register-resident weight rows ----------------
template<int N4>
__device__ __forceinline__ void loadrow(float* w, const float* p) {
#pragma unroll
  for (int k = 0; k < N4; ++k) {
    float4 q = ((const float4*)p)[k];
    w[4*k+0] = q.x; w[4*k+1] = q.y; w[4*k+2] = q.z; w[4*k+3] = q.w;
  }
}

// dot(w[0:4*K4], v[0:4*K4]) with LDS-broadcast float4 operand reads,
// 4 independent accumulators (beats fmac dep-chain latency)
template<int K4>
__device__ __forceinline__ float dotp(const float* w, const float4* v) {
  float a0 = 0.f, a1 = 0.f, a2 = 0.f, a3 = 0.f;
#pragma unroll
  for (int k = 0; k < K4; ++k) {
    float4 q = v[k];
    a0 = fmaf(w[4*k+0], q.x, a0);
    a1 = fmaf(w[4*k+1], q.y, a1);
    a2 = fmaf(w[4*k+2], q.z, a2);
    a3 = fmaf(w[4*k+3], q.w, a3);
  }
  return (a0 + a2) + (a1 + a3);
}

// One LSTM cell update for this lane's gate preactivation.
// Lane-group of 4 holds (i,f,g,o) for unit j; gsc/gof implement
// sigmoid via 0.5*tanh(x/2)+0.5 for gates i,f,o and plain tanh for g.
// Returns h (identical value in all 4 lanes of the group); c is the
// replicated cell state register.
__device__ __forceinline__ float cell_update(float pre, float gsc, float gof, float& c) {
  float a  = fmaf(gsc, tanh_f(pre * gsc), gof);
  float i_s = swz<0x001C>(a);   // lane base+0 : sigmoid(i)
  float f_s = swz<0x003C>(a);   // lane base+1 : sigmoid(f)
  float g_t = swz<0x005C>(a);   // lane base+2 : tanh(g)
  float o_s = swz<0x007C>(a);   // lane base+3 : sigmoid(o)
  c = fmaf(f_s, c, i_s * g_t);
  return o_s * tanh_f(c);
}

// Persistent kernel: one block per batch element, 256 threads.
// Thread t: j = t>>2 (unit), g = t&3 (gate i/f/g/o), weight row r = g*64+j
// kept in VGPRs. LDS ping-pong buffers hold [x:128 | h0:64 | h1:64].
__global__ __launch_bounds__(256, 1) void lstm_ae_kernel(
    const float* __restrict__ x,
    const float* __restrict__ eW0, const float* __restrict__ eU0,
    const float* __restrict__ ebi0, const float* __restrict__ ebh0,
    const float* __restrict__ eW1, const float* __restrict__ eU1,
    const float* __restrict__ ebi1, const float* __restrict__ ebh1,
    const float* __restrict__ dW0, const float* __restrict__ dU0,
    const float* __restrict__ dbi0, const float* __restrict__ dbh0,
    const float* __restrict__ dW1, const float* __restrict__ dU1,
    const float* __restrict__ dbi1, const float* __restrict__ dbh1,
    const float* __restrict__ fcW, const float* __restrict__ fcb,
    float* __restrict__ out)
{
  __shared__ __align__(16) float Abuf[256];
  __shared__ __align__(16) float Bbuf[256];

  const int tid = (int)threadIdx.x;
  const int b   = (int)blockIdx.x;
  const int j   = tid >> 2;
  const int g   = tid & 3;
  const int r   = g * HID + j;

  const float gsc = (g == 2) ? 1.0f : 0.5f;
  const float gof = (g == 2) ? 0.0f : 0.5f;

  // big layer row: [Wih row (din=128) | Whh row (64)] ; small layer: [64|64]
  float w0[DIN + HID];   // 192 VGPRs
  float w1[HID + HID];   // 128 VGPRs

  // ---------------- phase 1: fused 2-layer encoder ----------------
  loadrow<32>(w0,       eW0 + (size_t)r * DIN);
  loadrow<16>(w0 + 128, eU0 + (size_t)r * HID);
  loadrow<16>(w1,       eW1 + (size_t)r * HID);
  loadrow<16>(w1 + 64,  eU1 + (size_t)r * HID);
  float bs0 = ebi0[r] + ebh0[r];
  float bs1 = ebi1[r] + ebh1[r];

  const float* xb = x + (size_t)b * (T_SEQ * DIN);

  if (tid < 32) ((float4*)Abuf)[tid] = ((const float4*)xb)[tid];  // x_0
  if (tid >= 128) { Abuf[tid] = 0.f; Bbuf[tid] = 0.f; }           // h0,h1 = 0
  float c0 = 0.f, c1 = 0.f;
  __syncthreads();

  float* R = Abuf;   // read buffer for this step
  float* W = Bbuf;   // write buffer (next step's read buffer)

#pragma unroll 1
  for (int t = 0; t < T_SEQ; ++t) {
    float4 xn;
    const bool pf = (tid < 32) && (t + 1 < T_SEQ);
    if (pf) xn = ((const float4*)(xb + (size_t)(t + 1) * DIN))[tid];  // prefetch x_{t+1}

    // layer 0: operand [x_t | h0] = R[0..192)
    float pre0 = dotp<48>(w0, (const float4*)R) + bs0;
    {
      float h = cell_update(pre0, gsc, gof, c0);
      if (g == 0) W[128 + j] = h;
    }
    __syncthreads();                         // h0' visible; R reads done
    if (pf) ((float4*)W)[tid] = xn;          // stage x_{t+1} into write buffer

    // layer 1: operand [h0'(W+128) | h1_old(R+192)]
    float pre1 = dotp<16>(w1, (const float4*)(W + 128)) +
                 dotp<16>(w1 + 64, (const float4*)(R + 192)) + bs1;
    {
      float h = cell_update(pre1, gsc, gof, c1);
      if (g == 0) W[192 + j] = h;
    }
    __syncthreads();                         // h1' + x_{t+1} visible
    float* tmp = R; R = W; W = tmp;
  }

  // ---------------- transition: tanh on final states, x0 = 0 ----------------
  loadrow<32>(w0,       dW0 + (size_t)r * DIN);
  loadrow<16>(w0 + 128, dU0 + (size_t)r * HID);
  loadrow<16>(w1,       dW1 + (size_t)r * HID);
  loadrow<16>(w1 + 64,  dU1 + (size_t)r * HID);
  bs0 = dbi0[r] + dbh0[r];
  bs1 = dbi1[r] + dbh1[r];

  const int oo   = tid >> 1;   // fc output index [0,128)
  const int half = tid & 1;    // which 32-chunk of the 64-dot
  float fw[32];                // half an fc row in VGPRs
  loadrow<8>(fw, fcW + (size_t)oo * HID + half * 32);
  float fb = fcb[oo];

  c0 = tanh_f(c0);
  c1 = tanh_f(c1);
  if (tid < 128) R[128 + tid] = tanh_f(R[128 + tid]);  // tanh(h0), tanh(h1)
  if (tid < 128) R[tid] = 0.f;                         // x0 = zeros
  __syncthreads();

  float* outb = out + (size_t)b * (T_SEQ * DOUT);

  // ---------------- phase 2: autoregressive decoder ----------------
#pragma unroll 1
  for (int t = 0; t < T_SEQ; ++t) {
    // dec layer 0: operand [pred_{t-1} | h0] = R[0..192)
    float pre0 = dotp<48>(w0, (const float4*)R) + bs0;
    {
      float h = cell_update(pre0, gsc, gof, c0);
      if (g == 0) W[128 + j] = h;
    }
    __syncthreads();

    // dec layer 1: operand [h0'(W+128) | h1_old(R+192)]
    float pre1 = dotp<16>(w1, (const float4*)(W + 128)) +
                 dotp<16>(w1 + 64, (const float4*)(R + 192)) + bs1;
    {
      float h = cell_update(pre1, gsc, gof, c1);
      if (g == 0) W[192 + j] = h;
    }
    __syncthreads();                          // h1' visible for fc

    // fc: pred[oo] = dot(fcW[oo,:], h1') + fcb[oo]; pairs of lanes split k
    {
      const float4* hv = (const float4*)(W + 192 + half * 32);
      float a0 = 0.f, a1 = 0.f, a2 = 0.f, a3 = 0.f;
#pragma unroll
      for (int k = 0; k < 8; ++k) {
        float4 q = hv[k];
        a0 = fmaf(fw[4*k+0], q.x, a0);
        a1 = fmaf(fw[4*k+1], q.y, a1);
        a2 = fmaf(fw[4*k+2], q.z, a2);
        a3 = fmaf(fw[4*k+3], q.w, a3);
      }
      float s = (a0 + a2) + (a1 + a3);
      s += swz<0x041F>(s);                    // xor-1 pair reduce
      float pred = s + fb;
      if (half == 0) {
        W[oo] = pred;                         // feedback -> next step's x
        outb[(size_t)t * DOUT + oo] = pred;   // emit
      }
    }
    __syncthreads();
    float* tmp = R; R = W; W = tmp;
  }
}

extern "C" void kernel_launch(void* const* d_in, const int* in_sizes, int n_in,
                              void* d_out, int out_size, void* d_ws, size_t ws_size,
                              hipStream_t stream) {
  (void)in_sizes; (void)n_in; (void)d_ws; (void)ws_size; (void)out_size;
  const float* x    = (const float*)d_in[0];
  const float* eW0  = (const float*)d_in[1];
  const float* eU0  = (const float*)d_in[2];
  const float* ebi0 = (const float*)d_in[3];
  const float* ebh0 = (const float*)d_in[4];
  const float* eW1  = (const float*)d_in[5];
  const float* eU1  = (const float*)d_in[6];
  const float* ebi1 = (const float*)d_in[7];
  const float* ebh1 = (const float*)d_in[8];
  const float* dW0  = (const float*)d_in[9];
  const float* dU0  = (const float*)d_in[10];
  const float* dbi0 = (const float*)d_in[11];
  const float* dbh0 = (const float*)d_in[12];
  const float* dW1  = (const float*)d_in[13];
  const float* dU1  = (const float*)d_in[14];
  const float* dbi1 = (const float*)d_in[15];
  const float* dbh1 = (const float*)d_in[16];
  const float* fcW  = (const float*)d_in[17];
  const float* fcb  = (const float*)d_in[18];
  float* out = (float*)d_out;

  hipLaunchKernelGGL(lstm_ae_kernel, dim3(NBATCH), dim3(256), 0, stream,
                     x, eW0, eU0, ebi0, ebh0, eW1, eU1, ebi1, ebh1,
                     dW0, dU0, dbi0, dbh0, dW1, dU1, dbi1, dbh1,
                     fcW, fcb, out);
}

// Round 2
// 3072.006 us; speedup vs baseline: 1.3537x; 1.3537x over previous
//
#include <hip/hip_runtime.h>

#define T_SEQ 1024
#define NBATCH 256
#define DIN 128
#define HID 64
#define DOUT 128

// ---------------- fast math helpers ----------------
__device__ __forceinline__ float rcp_f(float x) { return __builtin_amdgcn_rcpf(x); }

// tanh(x) = 1 - 2/(1+e^{2x}); inf-safe
__device__ __forceinline__ float tanh_f(float x) {
  float m = __expf(2.0f * x);
  return fmaf(-2.0f, rcp_f(1.0f + m), 1.0f);
}

// ds_swizzle, BitMode: src_lane = ((lane & and) | or) ^ xor ; offset=(xor<<10)|(or<<5)|and
template<int IMM>
__device__ __forceinline__ float swz(float v) {
  return __uint_as_float((unsigned)__builtin_amdgcn_ds_swizzle((int)__float_as_uint(v), IMM));
}

// ---------------- register-resident weight rows ----------------
template<int N4>
__device__ __forceinline__ void loadrow(float* w, const float* p) {
#pragma unroll
  for (int k = 0; k < N4; ++k) {
    float4 q = ((const float4*)p)[k];
    w[4*k+0] = q.x; w[4*k+1] = q.y; w[4*k+2] = q.z; w[4*k+3] = q.w;
  }
}

// dot(w[0:4*K4], v[0:4*K4]) via LDS-broadcast float4 reads, 4 independent accumulators
template<int K4>
__device__ __forceinline__ float dotp(const float* w, const float4* v) {
  float a0 = 0.f, a1 = 0.f, a2 = 0.f, a3 = 0.f;
#pragma unroll
  for (int k = 0; k < K4; ++k) {
    float4 q = v[k];
    a0 = fmaf(w[4*k+0], q.x, a0);
    a1 = fmaf(w[4*k+1], q.y, a1);
    a2 = fmaf(w[4*k+2], q.z, a2);
    a3 = fmaf(w[4*k+3], q.w, a3);
  }
  return (a0 + a2) + (a1 + a3);
}

// LSTM nonlinearity. Lane-group of 8 = {gate i,f,g,o} x {k-half}; pre is the
// full (reduced) preactivation, identical in both halves. sigmoid via
// 0.5*tanh(x/2)+0.5 for i,f,o; tanh for g. c replicated across the 8 lanes.
__device__ __forceinline__ float cell_update(float pre, float gsc, float gof, float& c) {
  float a  = fmaf(gsc, tanh_f(pre * gsc), gof);
  float i_s = swz<0x0018>(a);   // gate 0, half 0
  float f_s = swz<0x0058>(a);   // gate 1
  float g_t = swz<0x0098>(a);   // gate 2
  float o_s = swz<0x00D8>(a);   // gate 3
  c = fmaf(f_s, c, i_s * g_t);
  return o_s * tanh_f(c);
}

// Persistent kernel: one block per batch element, 512 threads (8 waves, 2/SIMD).
// Thread t: half = t&1 (k-split), g = (t>>1)&3 (gate), j = t>>3 (unit).
// Weight row r = g*64+j, k-slice per half, held in arch VGPRs (<=176 floats).
// LDS ping-pong buffers: [x/pred:128 | h0:64 | h1:64] x 2.
__global__ __launch_bounds__(512, 2) void lstm_ae_kernel(
    const float* __restrict__ x,
    const float* __restrict__ eW0, const float* __restrict__ eU0,
    const float* __restrict__ ebi0, const float* __restrict__ ebh0,
    const float* __restrict__ eW1, const float* __restrict__ eU1,
    const float* __restrict__ ebi1, const float* __restrict__ ebh1,
    const float* __restrict__ dW0, const float* __restrict__ dU0,
    const float* __restrict__ dbi0, const float* __restrict__ dbh0,
    const float* __restrict__ dW1, const float* __restrict__ dU1,
    const float* __restrict__ dbi1, const float* __restrict__ dbh1,
    const float* __restrict__ fcW, const float* __restrict__ fcb,
    float* __restrict__ out)
{
  __shared__ __align__(16) float Abuf[256];
  __shared__ __align__(16) float Bbuf[256];

  const int tid  = (int)threadIdx.x;
  const int b    = (int)blockIdx.x;
  const int half = tid & 1;
  const int g    = (tid >> 1) & 3;
  const int j    = tid >> 3;
  const int r    = g * HID + j;

  const float gsc = (g == 2) ? 1.0f : 0.5f;
  const float gof = (g == 2) ? 0.0f : 0.5f;

  // layer0 k-slice: operand [x:128|h0:64], half0 = k[0,96), half1 = k[96,192)
  // layer1 k-slice: operand [h0:64|h1:64],  half0 = h0 side,  half1 = h1 side
  float w0[96];
  float w1[64];

  // ---------------- encoder weights ----------------
  if (half == 0) {
    loadrow<24>(w0, eW0 + (size_t)r * DIN);
    loadrow<16>(w1, eW1 + (size_t)r * HID);
  } else {
    loadrow<8>(w0,       eW0 + (size_t)r * DIN + 96);
    loadrow<16>(w0 + 32, eU0 + (size_t)r * HID);
    loadrow<16>(w1,      eU1 + (size_t)r * HID);
  }
  float bs0 = 0.5f * (ebi0[r] + ebh0[r]);   // each half contributes 1/2 bias
  float bs1 = 0.5f * (ebi1[r] + ebh1[r]);

  const float* xb = x + (size_t)b * (T_SEQ * DIN);

  if (tid < 32) ((float4*)Abuf)[tid] = ((const float4*)xb)[tid];   // x_0
  if (tid >= 128 && tid < 256) { Abuf[tid] = 0.f; Bbuf[tid] = 0.f; } // h0,h1 = 0
  float c0 = 0.f, c1 = 0.f;
  __syncthreads();

  float* R = Abuf;
  float* W = Bbuf;

  // ---------------- phase 1: fused 2-layer encoder ----------------
#pragma unroll 1
  for (int t = 0; t < T_SEQ; ++t) {
    float4 xn;
    const bool pf = (tid < 32) && (t + 1 < T_SEQ);
    if (pf) xn = ((const float4*)(xb + (size_t)(t + 1) * DIN))[tid];

    float p0 = dotp<24>(w0, (const float4*)(R + 96 * half)) + bs0;
    p0 += swz<0x041F>(p0);                       // combine k-halves (xor 1)
    {
      float h = cell_update(p0, gsc, gof, c0);
      if ((tid & 7) == 0) W[128 + j] = h;
    }
    __syncthreads();
    if (pf) ((float4*)W)[tid] = xn;              // stage x_{t+1}

    const float4* v1 = (const float4*)(half ? (R + 192) : (W + 128));
    float p1 = dotp<16>(w1, v1) + bs1;
    p1 += swz<0x041F>(p1);
    {
      float h = cell_update(p1, gsc, gof, c1);
      if ((tid & 7) == 0) W[192 + j] = h;
    }
    __syncthreads();
    float* tmp = R; R = W; W = tmp;
  }

  // ---------------- transition: decoder weights, tanh states, x0=0 ----------------
  if (half == 0) {
    loadrow<24>(w0, dW0 + (size_t)r * DIN);
    loadrow<16>(w1, dW1 + (size_t)r * HID);
  } else {
    loadrow<8>(w0,       dW0 + (size_t)r * DIN + 96);
    loadrow<16>(w0 + 32, dU0 + (size_t)r * HID);
    loadrow<16>(w1,      dU1 + (size_t)r * HID);
  }
  bs0 = 0.5f * (dbi0[r] + dbh0[r]);
  bs1 = 0.5f * (dbi1[r] + dbh1[r]);

  const int oo = tid >> 2;   // fc output [0,128)
  const int q  = tid & 3;    // 4-way k-split of the 64-dot
  float fw[16];
  loadrow<4>(fw, fcW + (size_t)oo * HID + q * 16);
  float fb = fcb[oo];

  c0 = tanh_f(c0);
  c1 = tanh_f(c1);
  if (tid < 128) { R[128 + tid] = tanh_f(R[128 + tid]); R[tid] = 0.f; }
  __syncthreads();

  float* outb = out + (size_t)b * (T_SEQ * DOUT);

  // ---------------- phase 2: autoregressive decoder ----------------
#pragma unroll 1
  for (int t = 0; t < T_SEQ; ++t) {
    float p0 = dotp<24>(w0, (const float4*)(R + 96 * half)) + bs0;
    p0 += swz<0x041F>(p0);
    {
      float h = cell_update(p0, gsc, gof, c0);
      if ((tid & 7) == 0) W[128 + j] = h;
    }
    __syncthreads();

    const float4* v1 = (const float4*)(half ? (R + 192) : (W + 128));
    float p1 = dotp<16>(w1, v1) + bs1;
    p1 += swz<0x041F>(p1);
    {
      float h = cell_update(p1, gsc, gof, c1);
      if ((tid & 7) == 0) W[192 + j] = h;
    }
    __syncthreads();                             // h1' visible for fc

    // fc: pred[oo] = fcW[oo,:] . h1' + fcb[oo]; 4 lanes split k, butterfly reduce
    {
      const float4* hv = (const float4*)(W + 192) + q * 4;
      float s = dotp<4>(fw, hv);
      s += swz<0x041F>(s);                       // xor 1
      s += swz<0x081F>(s);                       // xor 2
      float pred = s + fb;
      if (q == 0) {
        W[oo] = pred;                            // feedback -> next x
        outb[(size_t)t * DOUT + oo] = pred;
      }
    }
    __syncthreads();
    float* tmp = R; R = W; W = tmp;
  }
}

extern "C" void kernel_launch(void* const* d_in, const int* in_sizes, int n_in,
                              void* d_out, int out_size, void* d_ws, size_t ws_size,
                              hipStream_t stream) {
  (void)in_sizes; (void)n_in; (void)d_ws; (void)ws_size; (void)out_size;
  const float* x    = (const float*)d_in[0];
  const float* eW0  = (const float*)d_in[1];
  const float* eU0  = (const float*)d_in[2];
  const float* ebi0 = (const float*)d_in[3];
  const float* ebh0 = (const float*)d_in[4];
  const float* eW1  = (const float*)d_in[5];
  const float* eU1  = (const float*)d_in[6];
  const float* ebi1 = (const float*)d_in[7];
  const float* ebh1 = (const float*)d_in[8];
  const float* dW0  = (const float*)d_in[9];
  const float* dU0  = (const float*)d_in[10];
  const float* dbi0 = (const float*)d_in[11];
  const float* dbh0 = (const float*)d_in[12];
  const float* dW1  = (const float*)d_in[13];
  const float* dU1  = (const float*)d_in[14];
  const float* dbi1 = (const float*)d_in[15];
  const float* dbh1 = (const float*)d_in[16];
  const float* fcW  = (const float*)d_in[17];
  const float* fcb  = (const float*)d_in[18];
  float* out = (float*)d_out;

  hipLaunchKernelGGL(lstm_ae_kernel, dim3(NBATCH), dim3(512), 0, stream,
                     x, eW0, eU0, ebi0, ebh0, eW1, eU1, ebi1, ebh1,
                     dW0, dU0, dbi0, dbh0, dW1, dU1, dbi1, dbh1,
                     fcW, fcb, out);
}

// Round 3
// 2920.645 us; speedup vs baseline: 1.4239x; 1.0518x over previous
//
#include <hip/hip_runtime.h>

#define T_SEQ 1024
#define NBATCH 256
#define DIN 128
#define HID 64
#define DOUT 128

// LDS layout (floats), per ping-pong buffer of 352:
//  op0 [0..204):  layer-0 operand [x/pred:128 | h0:64] with 4-float pads so the
//                 four 48-float k-slices start at 0,52,104,156 (banks 0,20,8,28)
//                 x[k] -> k + 4*(k/48);  h0[j] -> 136+j (j<16) else 140+j
//  op1 [208..348): layer-1 operand [h0:64 | h1:64] padded to 36-float half-slices:
//                 h0[j] -> 208 + j + 4*(j>>5);  h1[j] -> 280 + j + 4*(j>>5)
//                 slice bases 208,244,280,316 -> banks 16,20,24,28
#define OP1 208
#define BUFSZ 352

__device__ __forceinline__ float rcp_f(float x) { return __builtin_amdgcn_rcpf(x); }

// tanh(x) = 1 - 2/(1+e^{2x}); inf-safe
__device__ __forceinline__ float tanh_f(float x) {
  float m = __expf(2.0f * x);
  return fmaf(-2.0f, rcp_f(1.0f + m), 1.0f);
}

// ds_swizzle BitMode: src = ((lane & and) | or) ^ xor ; offset=(xor<<10)|(or<<5)|and
template<int IMM>
__device__ __forceinline__ float swz(float v) {
  return __uint_as_float((unsigned)__builtin_amdgcn_ds_swizzle((int)__float_as_uint(v), IMM));
}

// quad-perm DPP butterfly add (lane^1: ctrl 0xB1, lane^2: ctrl 0x4E) — VALU pipe,
// avoids the LDS-pipe round trip of ds_swizzle on the serial reduce path.
template<int CTRL>
__device__ __forceinline__ float dpp_add(float v) {
  int p = __builtin_amdgcn_update_dpp(0, __float_as_int(v), CTRL, 0xF, 0xF, true);
  return v + __int_as_float(p);
}

template<int N4>
__device__ __forceinline__ void loadrow(float* w, const float* p) {
#pragma unroll
  for (int k = 0; k < N4; ++k) {
    float4 q = ((const float4*)p)[k];
    w[4*k+0] = q.x; w[4*k+1] = q.y; w[4*k+2] = q.z; w[4*k+3] = q.w;
  }
}

// dot(w, v[0:4*K4]) via LDS float4 reads, 4 independent accumulators
template<int K4>
__device__ __forceinline__ float dotp(const float* w, const float4* v) {
  float a0 = 0.f, a1 = 0.f, a2 = 0.f, a3 = 0.f;
#pragma unroll
  for (int k = 0; k < K4; ++k) {
    float4 q = v[k];
    a0 = fmaf(w[4*k+0], q.x, a0);
    a1 = fmaf(w[4*k+1], q.y, a1);
    a2 = fmaf(w[4*k+2], q.z, a2);
    a3 = fmaf(w[4*k+3], q.w, a3);
  }
  return (a0 + a2) + (a1 + a3);
}

// Lane map: q = tid&3 (k-quarter), g = (tid>>2)&3 (gate i,f,g,o), j = tid>>4 (unit).
// After the quad butterfly all 4 q-lanes hold the full preactivation of gate g.
// Gate broadcast within the 16-lane unit group: and=0x10, or=G<<2.
__device__ __forceinline__ float cell_update(float pre, float gsc, float gof, float& c) {
  float a  = fmaf(gsc, tanh_f(pre * gsc), gof);  // sigmoid for i,f,o ; tanh for g
  float i_s = swz<0x0010>(a);
  float f_s = swz<0x0090>(a);
  float g_t = swz<0x0110>(a);
  float o_s = swz<0x0190>(a);
  c = fmaf(f_s, c, i_s * g_t);
  return o_s * tanh_f(c);
}

__device__ __forceinline__ int xpos(int k) { return k + 4 * (k / 48); }

// One persistent block per batch element; 1024 threads = 16 waves = 4/SIMD.
// All weights in arch VGPRs: 48 (layer0 slice) + 32 (layer1 slice) + 8 (fc slice).
__global__ __launch_bounds__(1024, 4) void lstm_ae_kernel(
    const float* __restrict__ x,
    const float* __restrict__ eW0, const float* __restrict__ eU0,
    const float* __restrict__ ebi0, const float* __restrict__ ebh0,
    const float* __restrict__ eW1, const float* __restrict__ eU1,
    const float* __restrict__ ebi1, const float* __restrict__ ebh1,
    const float* __restrict__ dW0, const float* __restrict__ dU0,
    const float* __restrict__ dbi0, const float* __restrict__ dbh0,
    const float* __restrict__ dW1, const float* __restrict__ dU1,
    const float* __restrict__ dbi1, const float* __restrict__ dbh1,
    const float* __restrict__ fcW, const float* __restrict__ fcb,
    float* __restrict__ out)
{
  __shared__ __align__(16) float Abuf[BUFSZ];
  __shared__ __align__(16) float Bbuf[BUFSZ];

  const int tid = (int)threadIdx.x;
  const int b   = (int)blockIdx.x;
  const int q   = tid & 3;
  const int g   = (tid >> 2) & 3;
  const int j   = tid >> 4;
  const int r   = g * HID + j;

  const float gsc = (g == 2) ? 1.0f : 0.5f;
  const float gof = (g == 2) ? 0.0f : 0.5f;

  float w0[48];   // layer0 k-slice: k in [48q,48q+48) of [Wih row:128 | Whh row:64]
  float w1[32];   // layer1 k-slice: k in [32q,32q+32) of [Wih1 row:64 | Whh1 row:64]

  // ---------------- encoder weights ----------------
  if (q == 0)      loadrow<12>(w0, eW0 + (size_t)r * DIN);
  else if (q == 1) loadrow<12>(w0, eW0 + (size_t)r * DIN + 48);
  else if (q == 2) { loadrow<8>(w0, eW0 + (size_t)r * DIN + 96);
                     loadrow<4>(w0 + 32, eU0 + (size_t)r * HID); }
  else             loadrow<12>(w0, eU0 + (size_t)r * HID + 16);
  if (q < 2) loadrow<8>(w1, eW1 + (size_t)r * HID + 32 * q);
  else       loadrow<8>(w1, eU1 + (size_t)r * HID + 32 * (q - 2));
  float bs0 = ebi0[r] + ebh0[r];
  float bs1 = ebi1[r] + ebh1[r];

  const float* xb = x + (size_t)b * (T_SEQ * DIN);

  if (tid >= 136 && tid < BUFSZ) Abuf[tid] = 0.f;              // h-slots = 0
  if (tid < 32) {                                               // x_0 (padded)
    float4 v = ((const float4*)xb)[tid];
    ((float4*)Abuf)[tid + tid / 12] = v;
  }
  float c0 = 0.f, c1 = 0.f;
  __syncthreads();

  float* R = Abuf;
  float* W = Bbuf;

  // ---------------- phase 1: fused 2-layer encoder ----------------
#pragma unroll 1
  for (int t = 0; t < T_SEQ; ++t) {
    float4 xn;
    const bool pf = (tid < 32) && (t + 1 < T_SEQ);
    if (pf) xn = ((const float4*)(xb + (size_t)(t + 1) * DIN))[tid];

    float p0 = dotp<12>(w0, (const float4*)R + 13 * q);
    p0 = dpp_add<0xB1>(p0);             // xor 1
    p0 = dpp_add<0x4E>(p0);             // xor 2  -> full dot in all q-lanes
    p0 += bs0;
    float h0v = cell_update(p0, gsc, gof, c0);
    if ((tid & 15) == 0) W[(j < 16) ? 136 + j : 140 + j] = h0v;
    if ((tid & 15) == 1) W[OP1 + j + 4 * (j >> 5)] = h0v;
    __syncthreads();
    if (pf) ((float4*)W)[tid + tid / 12] = xn;                  // stage x_{t+1}

    const float* bb = (q < 2) ? W : R;                          // h0 new | h1 old
    float p1 = dotp<8>(w1, (const float4*)bb + 52 + 9 * q);
    p1 = dpp_add<0xB1>(p1);
    p1 = dpp_add<0x4E>(p1);
    p1 += bs1;
    float h1v = cell_update(p1, gsc, gof, c1);
    if ((tid & 15) == 0) W[280 + j + 4 * (j >> 5)] = h1v;
    __syncthreads();
    float* tmp = R; R = W; W = tmp;
  }

  // ---------------- transition: decoder weights, tanh states, x0 = 0 ----------------
  if (q == 0)      loadrow<12>(w0, dW0 + (size_t)r * DIN);
  else if (q == 1) loadrow<12>(w0, dW0 + (size_t)r * DIN + 48);
  else if (q == 2) { loadrow<8>(w0, dW0 + (size_t)r * DIN + 96);
                     loadrow<4>(w0 + 32, dU0 + (size_t)r * HID); }
  else             loadrow<12>(w0, dU0 + (size_t)r * HID + 16);
  if (q < 2) loadrow<8>(w1, dW1 + (size_t)r * HID + 32 * q);
  else       loadrow<8>(w1, dU1 + (size_t)r * HID + 32 * (q - 2));
  bs0 = dbi0[r] + dbh0[r];
  bs1 = dbi1[r] + dbh1[r];

  const int e  = tid & 7;      // fc k-slice (8 floats)
  const int oo = tid >> 3;     // fc output index [0,128)
  float fw[8];
  loadrow<2>(fw, fcW + (size_t)oo * HID + 8 * e);
  float fb = fcb[oo];

  c0 = tanh_f(c0);
  c1 = tanh_f(c1);
  if (tid < 64) {                       // tanh(h0_enc) in op0 h-slot
    int p = (tid < 16) ? 136 + tid : 140 + tid;
    R[p] = tanh_f(R[p]);
  } else if (tid < 128) {               // tanh(h1_enc) in op1 h1-slot
    int jj = tid - 64;
    int p = 280 + jj + 4 * (jj >> 5);
    R[p] = tanh_f(R[p]);
  } else if (tid < 264) {               // x0 = zeros (incl. pads)
    R[tid - 128] = 0.f;
  }
  __syncthreads();

  float* outb = out + (size_t)b * (T_SEQ * DOUT);

  // ---------------- phase 2: autoregressive decoder ----------------
#pragma unroll 1
  for (int t = 0; t < T_SEQ; ++t) {
    float p0 = dotp<12>(w0, (const float4*)R + 13 * q);
    p0 = dpp_add<0xB1>(p0);
    p0 = dpp_add<0x4E>(p0);
    p0 += bs0;
    float h0v = cell_update(p0, gsc, gof, c0);
    if ((tid & 15) == 0) W[(j < 16) ? 136 + j : 140 + j] = h0v;
    if ((tid & 15) == 1) W[OP1 + j + 4 * (j >> 5)] = h0v;
    __syncthreads();

    const float* bb = (q < 2) ? W : R;
    float p1 = dotp<8>(w1, (const float4*)bb + 52 + 9 * q);
    p1 = dpp_add<0xB1>(p1);
    p1 = dpp_add<0x4E>(p1);
    p1 += bs1;
    float h1v = cell_update(p1, gsc, gof, c1);
    if ((tid & 15) == 0) W[280 + j + 4 * (j >> 5)] = h1v;
    __syncthreads();                    // h1' visible for fc

    // fc: 8 lanes split the 64-dot; slice bases 70+2e(+1) f4 -> 8 distinct banks
    float s = dotp<2>(fw, (const float4*)W + 70 + 2 * e + (e >> 2));
    s = dpp_add<0xB1>(s);               // xor 1
    s = dpp_add<0x4E>(s);               // xor 2
    s += swz<0x101F>(s);                // xor 4
    float pred = s + fb;
    if (e == 0) {
      W[xpos(oo)] = pred;               // feedback -> next step's input
      outb[(size_t)t * DOUT + oo] = pred;
    }
    __syncthreads();
    float* tmp = R; R = W; W = tmp;
  }
}

extern "C" void kernel_launch(void* const* d_in, const int* in_sizes, int n_in,
                              void* d_out, int out_size, void* d_ws, size_t ws_size,
                              hipStream_t stream) {
  (void)in_sizes; (void)n_in; (void)d_ws; (void)ws_size; (void)out_size;
  const float* x    = (const float*)d_in[0];
  const float* eW0  = (const float*)d_in[1];
  const float* eU0  = (const float*)d_in[2];
  const float* ebi0 = (const float*)d_in[3];
  const float* ebh0 = (const float*)d_in[4];
  const float* eW1  = (const float*)d_in[5];
  const float* eU1  = (const float*)d_in[6];
  const float* ebi1 = (const float*)d_in[7];
  const float* ebh1 = (const float*)d_in[8];
  const float* dW0  = (const float*)d_in[9];
  const float* dU0  = (const float*)d_in[10];
  const float* dbi0 = (const float*)d_in[11];
  const float* dbh0 = (const float*)d_in[12];
  const float* dW1  = (const float*)d_in[13];
  const float* dU1  = (const float*)d_in[14];
  const float* dbi1 = (const float*)d_in[15];
  const float* dbh1 = (const float*)d_in[16];
  const float* fcW  = (const float*)d_in[17];
  const float* fcb  = (const float*)d_in[18];
  float* out = (float*)d_out;

  hipLaunchKernelGGL(lstm_ae_kernel, dim3(NBATCH), dim3(1024), 0, stream,
                     x, eW0, eU0, ebi0, ebh0, eW1, eU1, ebi1, ebh1,
                     dW0, dU0, dbi0, dbh0, dW1, dU1, dbi1, dbh1,
                     fcW, fcb, out);
}

// Round 4
// 2506.133 us; speedup vs baseline: 1.6594x; 1.1654x over previous
//
#include <hip/hip_runtime.h>

#define T_SEQ 1024
#define NBATCH 256
#define DIN 128
#define HID 64
#define DOUT 128

// ---------------- LDS layouts ----------------
// Encoder (per ping-pong buffer of 352 floats):
//  op0 [0..204):  [x:128 | h0:64], 4 k-slices of 48 at float-offsets 0,52,104,156
//                 x[k] -> k + 4*(k/48);  h0[j] -> 136+j (j<16) else 140+j
//  op1 [208..348): [h0new:64 | h1old:64]; slices of 32 padded to 36:
//                 h0[j] -> 208 + j + 4*(j>>5);  h1[j] -> 280 + j + 4*(j>>5)
// Decoder (overlaid on same buffers):
//  op0 [0..140):   [h1:64 | h0:64], pos(i) = i + 4*(i>>5); slices 0,36,72,108
//  op1 [144..284): [h0new:64 | h1old:64], pos = 144 + i + 4*(i>>5); slices 144,180,216,252
#define EOP1 208
#define DOP1 144
#define BUFSZ 352

__device__ __forceinline__ float rcp_f(float x) { return __builtin_amdgcn_rcpf(x); }

// tanh(x) = 1 - 2/(1+e^{2x}); inf-safe
__device__ __forceinline__ float tanh_f(float x) {
  float m = __expf(2.0f * x);
  return fmaf(-2.0f, rcp_f(1.0f + m), 1.0f);
}

// ds_swizzle BitMode (32-lane groups): src = ((lane & and) | or) ^ xor
template<int IMM>
__device__ __forceinline__ float swz(float v) {
  return __uint_as_float((unsigned)__builtin_amdgcn_ds_swizzle((int)__float_as_uint(v), IMM));
}

// quad-perm DPP butterfly add (lane^1: 0xB1, lane^2: 0x4E) on the VALU pipe
template<int CTRL>
__device__ __forceinline__ float dpp_add(float v) {
  int p = __builtin_amdgcn_update_dpp(0, __float_as_int(v), CTRL, 0xF, 0xF, true);
  return v + __int_as_float(p);
}

template<int N4>
__device__ __forceinline__ void loadrow(float* w, const float* p) {
#pragma unroll
  for (int k = 0; k < N4; ++k) {
    float4 q = ((const float4*)p)[k];
    w[4*k+0] = q.x; w[4*k+1] = q.y; w[4*k+2] = q.z; w[4*k+3] = q.w;
  }
}

template<int K4>
__device__ __forceinline__ float dotp(const float* w, const float4* v) {
  float a0 = 0.f, a1 = 0.f, a2 = 0.f, a3 = 0.f;
#pragma unroll
  for (int k = 0; k < K4; ++k) {
    float4 q = v[k];
    a0 = fmaf(w[4*k+0], q.x, a0);
    a1 = fmaf(w[4*k+1], q.y, a1);
    a2 = fmaf(w[4*k+2], q.z, a2);
    a3 = fmaf(w[4*k+3], q.w, a3);
  }
  return (a0 + a2) + (a1 + a3);
}

// Lane map: q = tid&3 (k-quarter), g = (tid>>2)&3 (gate i,f,g,o), j = tid>>4 (unit).
// Gate broadcast within the 16-lane unit group (and=0x10 keeps the group bit
// within ds_swizzle's 32-lane domain; bit5 preserved implicitly).
__device__ __forceinline__ float cell_update(float pre, float gsc, float gof, float& c) {
  float a  = fmaf(gsc, tanh_f(pre * gsc), gof);  // sigmoid for i,f,o ; tanh for g
  float i_s = swz<0x0010>(a);
  float f_s = swz<0x0090>(a);
  float g_t = swz<0x0110>(a);
  float o_s = swz<0x0190>(a);
  c = fmaf(f_s, c, i_s * g_t);
  return o_s * tanh_f(c);
}

__device__ __forceinline__ int xpos(int k)  { return k + 4 * (k / 48); }   // enc x slot
__device__ __forceinline__ int ppos(int i)  { return i + 4 * (i >> 5); }   // dec padded slot

// ---------------- prep kernel: C0 = dWih0 @ fcW  [256x64], fcbt = dWih0 @ fcb ----------------
__global__ void prep_kernel(const float* __restrict__ dWih0,
                            const float* __restrict__ fcW,
                            const float* __restrict__ fcb,
                            float* __restrict__ ws) {
  const int r = (int)blockIdx.x;           // 256 blocks
  const int jj = (int)threadIdx.x;         // 64 threads
  const float* wr = dWih0 + (size_t)r * DIN;
  float acc = 0.f;
  for (int o = 0; o < DIN; ++o) acc = fmaf(wr[o], fcW[(size_t)o * HID + jj], acc);
  ws[(size_t)r * HID + jj] = acc;
  if (jj == 0) {
    float a = 0.f;
    for (int o = 0; o < DIN; ++o) a = fmaf(wr[o], fcb[o], a);
    ws[256 * HID + r] = a;
  }
}

// ---------------- main persistent kernel: 1 block / batch element, 1024 threads ----------------
__global__ __launch_bounds__(1024, 4) void lstm_ae_kernel(
    const float* __restrict__ x,
    const float* __restrict__ eW0, const float* __restrict__ eU0,
    const float* __restrict__ ebi0, const float* __restrict__ ebh0,
    const float* __restrict__ eW1, const float* __restrict__ eU1,
    const float* __restrict__ ebi1, const float* __restrict__ ebh1,
    const float* __restrict__ dW0, const float* __restrict__ dU0,
    const float* __restrict__ dbi0, const float* __restrict__ dbh0,
    const float* __restrict__ dW1, const float* __restrict__ dU1,
    const float* __restrict__ dbi1, const float* __restrict__ dbh1,
    const float* __restrict__ fcW, const float* __restrict__ fcb,
    const float* __restrict__ ws,
    float* __restrict__ out)
{
  __shared__ __align__(16) float Abuf[BUFSZ];
  __shared__ __align__(16) float Bbuf[BUFSZ];

  const int tid = (int)threadIdx.x;
  const int b   = (int)blockIdx.x;
  const int q   = tid & 3;
  const int g   = (tid >> 2) & 3;
  const int j   = tid >> 4;
  const int r   = g * HID + j;

  const float gsc = (g == 2) ? 1.0f : 0.5f;
  const float gof = (g == 2) ? 0.0f : 0.5f;

  float w0[48];
  float w1[32];

  // ---------------- encoder weights ----------------
  if (q == 0)      loadrow<12>(w0, eW0 + (size_t)r * DIN);
  else if (q == 1) loadrow<12>(w0, eW0 + (size_t)r * DIN + 48);
  else if (q == 2) { loadrow<8>(w0, eW0 + (size_t)r * DIN + 96);
                     loadrow<4>(w0 + 32, eU0 + (size_t)r * HID); }
  else             loadrow<12>(w0, eU0 + (size_t)r * HID + 16);
  if (q < 2) loadrow<8>(w1, eW1 + (size_t)r * HID + 32 * q);
  else       loadrow<8>(w1, eU1 + (size_t)r * HID + 32 * (q - 2));
  float bs0 = ebi0[r] + ebh0[r];
  float bs1 = ebi1[r] + ebh1[r];

  const float* xb = x + (size_t)b * (T_SEQ * DIN);

  if (tid >= 136 && tid < BUFSZ) Abuf[tid] = 0.f;              // h-slots = 0
  if (tid < 32) {
    float4 v = ((const float4*)xb)[tid];
    ((float4*)Abuf)[tid + tid / 12] = v;                       // x_0 (padded)
  }
  float c0 = 0.f, c1 = 0.f;
  __syncthreads();

  // ---------------- phase 1: fused 2-layer encoder ----------------
  auto enc_step = [&](float* R, float* W, int t) {
    float4 xn;
    const bool pf = (tid < 32) && (t + 1 < T_SEQ);
    if (pf) xn = ((const float4*)(xb + (size_t)(t + 1) * DIN))[tid];

    float p0 = dotp<12>(w0, (const float4*)R + 13 * q);
    p0 = dpp_add<0xB1>(p0);
    p0 = dpp_add<0x4E>(p0);
    p0 += bs0;
    float h0v = cell_update(p0, gsc, gof, c0);
    if ((tid & 15) < 2)
      W[(tid & 15) ? (EOP1 + j + 4 * (j >> 5)) : ((j < 16) ? 136 + j : 140 + j)] = h0v;
    __syncthreads();
    if (pf) ((float4*)W)[tid + tid / 12] = xn;                 // stage x_{t+1}

    const float* bb = (q < 2) ? W : R;
    float p1 = dotp<8>(w1, (const float4*)bb + 52 + 9 * q);
    p1 = dpp_add<0xB1>(p1);
    p1 = dpp_add<0x4E>(p1);
    p1 += bs1;
    float h1v = cell_update(p1, gsc, gof, c1);
    if ((tid & 15) == 0) W[280 + j + 4 * (j >> 5)] = h1v;
    __syncthreads();
  };

#pragma unroll 1
  for (int t = 0; t < T_SEQ; t += 2) {
    enc_step(Abuf, Bbuf, t);
    enc_step(Bbuf, Abuf, t + 1);
  }
  float* R = Abuf;    // final encoder state lives here (even # of swaps)
  float* W = Bbuf;

  // ---------------- transition: decoder weights + re-layout states ----------------
  // dec layer-0 operates on [h1 | h0] via composite C0 = dWih0 @ fcW (from ws)
  const float* C0   = ws;
  const float* fcbt_arr = ws + 256 * HID;
  if (q < 2) loadrow<8>(w0, C0  + (size_t)r * HID + 32 * q);
  else       loadrow<8>(w0, dU0 + (size_t)r * HID + 32 * (q - 2));
  if (q < 2) loadrow<8>(w1, dW1 + (size_t)r * HID + 32 * q);
  else       loadrow<8>(w1, dU1 + (size_t)r * HID + 32 * (q - 2));
  float bs0d = dbi0[r] + dbh0[r];
  float bs1d = dbi1[r] + dbh1[r];
  float fcbt = fcbt_arr[r];

  const int e  = tid & 7;      // fc k-slice (8 floats)
  const int oo = tid >> 3;     // fc output index [0,128)
  float fw[8];
  loadrow<2>(fw, fcW + (size_t)oo * HID + 8 * e);
  float fb = fcb[oo];

  c0 = tanh_f(c0);
  c1 = tanh_f(c1);
  float hv = 0.f;
  if (tid < 64)        hv = tanh_f(R[(tid < 16) ? 136 + tid : 140 + tid]);        // h0enc
  else if (tid < 128)  { int jj = tid - 64; hv = tanh_f(R[280 + jj + 4*(jj>>5)]); } // h1enc
  __syncthreads();
  if (tid < 64)        R[72 + tid + 4 * (tid >> 5)] = hv;        // op0 h0 slot
  else if (tid < 128)  { int jj = tid - 64; R[216 + jj + 4*(jj>>5)] = hv; } // op1 h1old
  else if (tid < 196)  R[tid - 128] = 0.f;                       // op0 h1 slot = 0 (t=0: pred_{-1}=0)
  __syncthreads();

  float* outb = out + (size_t)b * (T_SEQ * DOUT);

  // ---------------- phase 2: autoregressive decoder (fc folded via C0) ----------------
  auto dec_step = [&](float* R_, float* W_, int t) {
    // layer-0 dot on [h1_{t-1} | h0_{t-1}]  (K=128)
    float p0 = dotp<8>(w0, (const float4*)R_ + 9 * q);
    // fc for pred_{t-1} (output only; off the critical path), reads R_ h1 slot
    float s = dotp<2>(fw, (const float4*)R_ + 2 * e + (e >> 2));
    p0 = dpp_add<0xB1>(p0);
    p0 = dpp_add<0x4E>(p0);
    p0 += bs0d;
    if (t > 0) p0 += fcbt;                      // composite fcb term (absent at t=0)
    float h0v = cell_update(p0, gsc, gof, c0);
    if ((tid & 15) < 2)
      W_[(tid & 15) ? (72 + j + 4 * (j >> 5)) : (DOP1 + j + 4 * (j >> 5))] = h0v;
    s = dpp_add<0xB1>(s);
    s = dpp_add<0x4E>(s);
    s += swz<0x101F>(s);                        // xor 4
    if (e == 0 && t > 0) outb[(size_t)(t - 1) * DOUT + oo] = s + fb;
    __syncthreads();

    const float* bb = (q < 2) ? W_ : R_;        // [h0new | h1old]
    float p1 = dotp<8>(w1, (const float4*)bb + 36 + 9 * q);
    p1 = dpp_add<0xB1>(p1);
    p1 = dpp_add<0x4E>(p1);
    p1 += bs1d;
    float h1v = cell_update(p1, gsc, gof, c1);
    if ((tid & 15) < 2)
      W_[(tid & 15) ? (j + 4 * (j >> 5)) : (216 + j + 4 * (j >> 5))] = h1v;
    __syncthreads();
  };

#pragma unroll 1
  for (int t = 0; t < T_SEQ; t += 2) {
    dec_step(R, W, t);
    dec_step(W, R, t + 1);
  }

  // epilogue: pred_{1023} from final h1 (in R)
  float s = dotp<2>(fw, (const float4*)R + 2 * e + (e >> 2));
  s = dpp_add<0xB1>(s);
  s = dpp_add<0x4E>(s);
  s += swz<0x101F>(s);
  if (e == 0) outb[(size_t)(T_SEQ - 1) * DOUT + oo] = s + fb;
}

extern "C" void kernel_launch(void* const* d_in, const int* in_sizes, int n_in,
                              void* d_out, int out_size, void* d_ws, size_t ws_size,
                              hipStream_t stream) {
  (void)in_sizes; (void)n_in; (void)ws_size; (void)out_size;
  const float* x    = (const float*)d_in[0];
  const float* eW0  = (const float*)d_in[1];
  const float* eU0  = (const float*)d_in[2];
  const float* ebi0 = (const float*)d_in[3];
  const float* ebh0 = (const float*)d_in[4];
  const float* eW1  = (const float*)d_in[5];
  const float* eU1  = (const float*)d_in[6];
  const float* ebi1 = (const float*)d_in[7];
  const float* ebh1 = (const float*)d_in[8];
  const float* dW0  = (const float*)d_in[9];
  const float* dU0  = (const float*)d_in[10];
  const float* dbi0 = (const float*)d_in[11];
  const float* dbh0 = (const float*)d_in[12];
  const float* dW1  = (const float*)d_in[13];
  const float* dU1  = (const float*)d_in[14];
  const float* dbi1 = (const float*)d_in[15];
  const float* dbh1 = (const float*)d_in[16];
  const float* fcW  = (const float*)d_in[17];
  const float* fcb  = (const float*)d_in[18];
  float* ws  = (float*)d_ws;
  float* out = (float*)d_out;

  hipLaunchKernelGGL(prep_kernel, dim3(256), dim3(64), 0, stream, dW0, fcW, fcb, ws);
  hipLaunchKernelGGL(lstm_ae_kernel, dim3(NBATCH), dim3(1024), 0, stream,
                     x, eW0, eU0, ebi0, ebh0, eW1, eU1, ebi1, ebh1,
                     dW0, dU0, dbi0, dbh0, dW1, dU1, dbi1, dbh1,
                     fcW, fcb, ws, out);
}